// Round 4
// baseline (1438.698 us; speedup 1.0000x reference)
//
#include <hip/hip_runtime.h>
#include <hip/hip_bf16.h>

#define NPTS 200000
#define CIN 64
#define COUT 64
#define KVOL 27
#define NPAIRS 100000
#define NPAIRS_TOT (KVOL * NPAIRS)                       // 2,700,000
#define NTILES (NPTS / 16)                               // 12,500 output tiles of 16 rows
#define NKEYS (NTILES * KVOL)                            // 337,500 (tile,k) buckets
#define SCAN_ITEMS 2048
#define NSCANB ((NKEYS + SCAN_ITEMS - 1) / SCAN_ITEMS)   // 165
#define BN_EPS 1e-5f

static_assert(NPTS % 16 == 0, "tiles");
static_assert(NTILES % 4 == 0, "4 waves/block");
static_assert(NSCANB <= 256, "single-block top scan");
static_assert(NPTS * CIN % (256 * 8) == 0, "fprep exact grid");

typedef __attribute__((ext_vector_type(8))) short short8;   // 8 bf16 (4 VGPRs)
typedef __attribute__((ext_vector_type(4))) float f32x4;

__device__ inline ushort f2bf(float x) {
    union { __hip_bfloat16 h; ushort u; } cv;
    cv.h = __float2bfloat16(x);   // RNE
    return cv.u;
}

// ---------- preprocessing ----------
// R3 post-mortem: conv kernel was TA/line-visit bound (~260 cache-line visits per
// 16-entry chunk; 1.9% MFMA, 6% VALU, 5% HBM, 0 bank conflict). Fixes: bf16 feats
// (halves feats lines, kills redundant visits + in-loop cvt) and LDS-staged weights
// (kills the per-wave-per-k 128-line bfrag reload that VGPR_Count=48 betrayed).

// feats fp32 [NPTS][64] -> bf16 [NPTS][64] (rows = 128B = 2 lines)
__global__ __launch_bounds__(256) void fprep_kernel(const float* __restrict__ feats,
                                                    ushort* __restrict__ fb) {
    const int i = blockIdx.x * 256 + threadIdx.x;     // 8 elems/thread, exact grid
    const f32x4 v0 = *(const f32x4*)(feats + (size_t)i * 8);
    const f32x4 v1 = *(const f32x4*)(feats + (size_t)i * 8 + 4);
    short8 o;
    #pragma unroll
    for (int e = 0; e < 4; ++e) {
        o[e]     = (short)f2bf(v0[e]);
        o[e + 4] = (short)f2bf(v1[e]);
    }
    *(short8*)(fb + (size_t)i * 8) = o;
}

// W[k][cin][cout] fp32  ->  Wt[k][cout][cin] bf16 (B-frags load as 16B)
__global__ __launch_bounds__(256) void wprep_kernel(const float* __restrict__ wk,
                                                    ushort* __restrict__ wt) {
    const int i = blockIdx.x * 256 + threadIdx.x;     // over KVOL*64*64 = 110,592
    if (i >= KVOL * CIN * COUT) return;
    const int k = i >> 12, r = i & 4095, co = r >> 6, ci = r & 63;
    wt[i] = f2bf(wk[(k << 12) | (ci << 6) | co]);
}

__global__ __launch_bounds__(256) void hist_kernel(const int* __restrict__ omap,
                                                   int* __restrict__ cnt) {
    for (int i = blockIdx.x * 256 + threadIdx.x; i < NPAIRS_TOT; i += gridDim.x * 256) {
        const int k = i / NPAIRS;                     // magic-mul div
        atomicAdd(&cnt[(omap[i] >> 4) * KVOL + k], 1);
    }
}

// 2-level exclusive scan over NKEYS counters (165 blocks x 2048 items).
__global__ __launch_bounds__(256) void scan1_kernel(const int* __restrict__ cnt,
                                                    int* __restrict__ offs,
                                                    int* __restrict__ bsum) {
    __shared__ int s[256];
    const int t = threadIdx.x;
    const int base = blockIdx.x * SCAN_ITEMS + t * 8;
    int v[8]; int sum = 0;
    #pragma unroll
    for (int i = 0; i < 8; ++i) {
        const int idx = base + i;
        v[i] = (idx < NKEYS) ? cnt[idx] : 0;
        sum += v[i];
    }
    s[t] = sum;
    __syncthreads();
    for (int off = 1; off < 256; off <<= 1) {         // Hillis-Steele inclusive
        const int x = (t >= off) ? s[t - off] : 0;
        __syncthreads();
        s[t] += x;
        __syncthreads();
    }
    if (t == 255) bsum[blockIdx.x] = s[255];
    int run = s[t] - sum;                             // exclusive prefix of this thread
    #pragma unroll
    for (int i = 0; i < 8; ++i) {
        const int idx = base + i;
        if (idx < NKEYS) offs[idx] = run;
        run += v[i];
    }
}

__global__ __launch_bounds__(256) void scan2_kernel(int* __restrict__ bsum) {
    __shared__ int s[256];
    const int t = threadIdx.x;
    const int v = (t < NSCANB) ? bsum[t] : 0;
    s[t] = v;
    __syncthreads();
    for (int off = 1; off < 256; off <<= 1) {
        const int x = (t >= off) ? s[t - off] : 0;
        __syncthreads();
        s[t] += x;
        __syncthreads();
    }
    if (t < NSCANB) bsum[t] = s[t] - v;               // exclusive block offsets
}

__global__ __launch_bounds__(256) void scan3_kernel(int* __restrict__ offs,
                                                    int* __restrict__ cursor,
                                                    const int* __restrict__ bsum) {
    const int base = blockIdx.x * SCAN_ITEMS + threadIdx.x * 8;
    const int add = bsum[blockIdx.x];
    if (blockIdx.x == 0 && threadIdx.x == 0) offs[NKEYS] = NPAIRS_TOT;  // sentinel
    #pragma unroll
    for (int i = 0; i < 8; ++i) {
        const int idx = base + i;
        if (idx < NKEYS) {
            const int v = offs[idx] + add;
            offs[idx] = v;
            cursor[idx] = v;                          // fill cursors start at bucket base
        }
    }
}

// payload = in_row (18b) | local_out_row (4b) << 18
__global__ __launch_bounds__(256) void fill_kernel(const int* __restrict__ imap,
                                                   const int* __restrict__ omap,
                                                   int* __restrict__ cursor,
                                                   unsigned* __restrict__ payload) {
    for (int i = blockIdx.x * 256 + threadIdx.x; i < NPAIRS_TOT; i += gridDim.x * 256) {
        const int k = i / NPAIRS;
        const int o = omap[i];
        const int key = (o >> 4) * KVOL + k;
        const int pos = atomicAdd(&cursor[key], 1);
        payload[pos] = (unsigned)imap[i] | ((unsigned)(o & 15) << 18);
    }
}

// ---------- output-stationary conv ----------
// Wave owns one 16-row output tile (LDS [16][65] f32). Per k: block cooperatively
// stages wt[k] (8KB, double-buffered, XOR-swizzled so stride-128B ds_read_b128 is
// ~2-way not 16-way), waves read bfrag from LDS; chunks of <=16 bucket entries:
//   A[m=lane&15][kin=q*8+e] as two 16B bf16 loads (each row line visited once)
//   D: pair=q*4+r, cout=nt*16+(lane&15)
// Scatter via LDS atomicAdd; epilogue BN+ReLU + single coalesced write.
__global__ __launch_bounds__(256, 4) void conv_gather_kernel(
    const ushort* __restrict__ fb,        // bf16 feats [NPTS][64]
    const ushort* __restrict__ wt,        // bf16 [KVOL][COUT][CIN]
    const unsigned* __restrict__ payload,
    const int* __restrict__ offs,         // NKEYS+1 (sentinel)
    const float* __restrict__ gamma,
    const float* __restrict__ beta,
    const float* __restrict__ rmean,
    const float* __restrict__ rvar,
    float* __restrict__ out)
{
    __shared__ float tile[4][16 * 65];    // 16.64 KB
    __shared__ ushort wbuf[2][4096];      // 2 x 8 KB weight double-buffer
    const int lane = threadIdx.x & 63;
    const int wave = threadIdx.x >> 6;
    const int m = lane & 15;
    const int q = lane >> 4;
    const int t = blockIdx.x * 4 + wave;

    for (int i = lane; i < 16 * 65; i += 64) tile[wave][i] = 0.f;

    const float sc = gamma[lane] * rsqrtf(rvar[lane] + BN_EPS);
    const float bi = beta[lane] - rmean[lane] * sc;

    // cooperative stage of wt[k] (8KB = 512 x 16B; 256 thr x 2), swizzle on write:
    // linear byte B lands at B ^ (((B>>7)&7)<<4)  (involution, row bits preserved)
    auto stagef = [&](int k, int b) {
        const char* src = (const char*)wt + (size_t)k * 8192;
        #pragma unroll
        for (int j = 0; j < 2; ++j) {
            const int byte = (threadIdx.x + j * 256) * 16;
            const uint4 v = *(const uint4*)(src + byte);
            const int sw = byte ^ (((byte >> 7) & 7) << 4);
            *(uint4*)((char*)wbuf[b] + sw) = v;
        }
    };

    stagef(0, 0);
    int e0 = offs[t * KVOL];

    for (int k = 0; k < KVOL; ++k) {
        __syncthreads();                  // my stage writes drained + all waves done
                                          // reading wbuf[(k+1)&1] in iter k-1
        if (k + 1 < KVOL) stagef(k + 1, (k + 1) & 1);

        short8 bfrag[2][4];               // read with same XOR as staged
        #pragma unroll
        for (int h = 0; h < 2; ++h)
            #pragma unroll
            for (int nt = 0; nt < 4; ++nt) {
                const int byte = (nt * 16 + m) * 128 + h * 64 + q * 16;
                const int sw = byte ^ ((m & 7) << 4);   // (byte>>7)&7 == m&7 here
                bfrag[h][nt] = *(const short8*)((const char*)wbuf[k & 1] + sw);
            }

        const int e1 = offs[t * KVOL + k + 1];

        for (int base = e0; base < e1; base += 16) {
            const int ei = base + m;
            unsigned pl = 0u;
            short8 a0 = {0, 0, 0, 0, 0, 0, 0, 0};
            short8 a1 = {0, 0, 0, 0, 0, 0, 0, 0};
            if (ei < e1) {
                pl = payload[ei];
                const ushort* fr = fb + (size_t)(pl & 0x3FFFFu) * 64 + q * 8;
                a0 = *(const short8*)(fr);
                a1 = *(const short8*)(fr + 32);
            }

            unsigned plr[4];
            #pragma unroll
            for (int r = 0; r < 4; ++r) plr[r] = (unsigned)__shfl((int)pl, q * 4 + r);

            f32x4 acc[4];
            #pragma unroll
            for (int nt = 0; nt < 4; ++nt) acc[nt] = (f32x4){0.f, 0.f, 0.f, 0.f};
            #pragma unroll
            for (int nt = 0; nt < 4; ++nt) {
                acc[nt] = __builtin_amdgcn_mfma_f32_16x16x32_bf16(a0, bfrag[0][nt], acc[nt], 0, 0, 0);
                acc[nt] = __builtin_amdgcn_mfma_f32_16x16x32_bf16(a1, bfrag[1][nt], acc[nt], 0, 0, 0);
            }

            #pragma unroll
            for (int r = 0; r < 4; ++r) {
                if (base + q * 4 + r < e1) {
                    const int l = (int)((plr[r] >> 18) & 15u);
                    #pragma unroll
                    for (int nt = 0; nt < 4; ++nt)
                        atomicAdd(&tile[wave][l * 65 + nt * 16 + m], acc[nt][r]);
                }
            }
        }
        e0 = e1;
    }

    __syncthreads();   // drain own ds ops before re-read
    #pragma unroll
    for (int r = 0; r < 16; ++r) {
        const float v = tile[wave][r * 65 + lane];
        out[((size_t)t * 16 + r) * COUT + lane] = fmaxf(v * sc + bi, 0.f);
    }
}

extern "C" void kernel_launch(void* const* d_in, const int* in_sizes, int n_in,
                              void* d_out, int out_size, void* d_ws, size_t ws_size,
                              hipStream_t stream) {
    const float* feats = (const float*)d_in[0];
    const float* wk    = (const float*)d_in[1];
    const float* gamma = (const float*)d_in[2];
    const float* beta  = (const float*)d_in[3];
    const float* rmean = (const float*)d_in[4];
    const float* rvar  = (const float*)d_in[5];
    const int* imap    = (const int*)d_in[6];
    const int* omap    = (const int*)d_in[7];
    float* out         = (float*)d_out;

    // workspace carve — byte-verified disjoint:
    //   cnt     [0        , 1,350,000)
    //   offs    [2,097,152, 3,447,156)   (NKEYS+1 ints)
    //   bsum    [4,194,304, 4,194,964)
    //   cursor  [5,242,880, 6,592,880)
    //   wt      [7,340,032, 7,561,216)
    //   payload [8,388,608, 19,188,608)
    //   fb      [20,971,520, 46,571,520) (25.6MB bf16 feats; ws >= 51.2MB per R0)
    char* ws = (char*)d_ws;
    int* cnt          = (int*)(ws);
    int* offs         = (int*)(ws + (2u << 20));
    int* bsum         = (int*)(ws + (4u << 20));
    int* cursor       = (int*)(ws + (5u << 20));
    ushort* wt        = (ushort*)(ws + (7u << 20));
    unsigned* payload = (unsigned*)(ws + (8u << 20));
    ushort* fb        = (ushort*)(ws + (20u << 20));

    hipMemsetAsync(cnt, 0, NKEYS * sizeof(int), stream);
    fprep_kernel<<<NPTS * CIN / (256 * 8), 256, 0, stream>>>(feats, fb);
    wprep_kernel<<<(KVOL * CIN * COUT + 255) / 256, 256, 0, stream>>>(wk, wt);
    hist_kernel<<<2048, 256, 0, stream>>>(omap, cnt);
    scan1_kernel<<<NSCANB, 256, 0, stream>>>(cnt, offs, bsum);
    scan2_kernel<<<1, 256, 0, stream>>>(bsum);
    scan3_kernel<<<NSCANB, 256, 0, stream>>>(offs, cursor, bsum);
    fill_kernel<<<2048, 256, 0, stream>>>(imap, omap, cursor, payload);
    conv_gather_kernel<<<NTILES / 4, 256, 0, stream>>>(
        fb, wt, payload, offs, gamma, beta, rmean, rvar, out);
}

// Round 5
// 1421.370 us; speedup vs baseline: 1.0122x; 1.0122x over previous
//
#include <hip/hip_runtime.h>
#include <hip/hip_bf16.h>

#define NPTS 200000
#define CIN 64
#define COUT 64
#define KVOL 27
#define NPAIRS 100000
#define NPAIRS_TOT (KVOL * NPAIRS)                       // 2,700,000
#define NTILES (NPTS / 16)                               // 12,500 output tiles of 16 rows
#define NKEYS (NTILES * KVOL)                            // 337,500 (tile,k) buckets
#define SCAN_ITEMS 2048
#define NSCANB ((NKEYS + SCAN_ITEMS - 1) / SCAN_ITEMS)   // 165
#define BN_EPS 1e-5f

static_assert(NPTS % 16 == 0, "tiles");
static_assert(NSCANB <= 256, "single-block top scan");
static_assert(NPTS * CIN % (256 * 8) == 0, "fprep exact grid");

typedef __attribute__((ext_vector_type(8))) short short8;   // 8 bf16 (4 VGPRs)
typedef __attribute__((ext_vector_type(4))) float f32x4;

__device__ inline ushort f2bf(float x) {
    union { __hip_bfloat16 h; ushort u; } cv;
    cv.h = __float2bfloat16(x);   // RNE
    return cv.u;
}

// ---------- preprocessing (counting sort by (out_tile, k)) ----------

// feats fp32 [NPTS][64] -> bf16 [NPTS][64] (row = 128B = 1 line)
__global__ __launch_bounds__(256) void fprep_kernel(const float* __restrict__ feats,
                                                    ushort* __restrict__ fb) {
    const int i = blockIdx.x * 256 + threadIdx.x;     // 8 elems/thread, exact grid
    const f32x4 v0 = *(const f32x4*)(feats + (size_t)i * 8);
    const f32x4 v1 = *(const f32x4*)(feats + (size_t)i * 8 + 4);
    short8 o;
    #pragma unroll
    for (int e = 0; e < 4; ++e) {
        o[e]     = (short)f2bf(v0[e]);
        o[e + 4] = (short)f2bf(v1[e]);
    }
    *(short8*)(fb + (size_t)i * 8) = o;
}

// W[k][cin][cout] fp32  ->  Wt[k][cout][cin] bf16 (B-frags load as 16B)
__global__ __launch_bounds__(256) void wprep_kernel(const float* __restrict__ wk,
                                                    ushort* __restrict__ wt) {
    const int i = blockIdx.x * 256 + threadIdx.x;     // over KVOL*64*64 = 110,592
    if (i >= KVOL * CIN * COUT) return;
    const int k = i >> 12, r = i & 4095, co = r >> 6, ci = r & 63;
    wt[i] = f2bf(wk[(k << 12) | (ci << 6) | co]);
}

// 2D grid: blockIdx.y = k (no integer div, contiguous map reads)
__global__ __launch_bounds__(256) void hist_kernel(const int* __restrict__ omap,
                                                   int* __restrict__ cnt) {
    const int k = blockIdx.y;
    const int i = blockIdx.x * 256 + threadIdx.x;
    if (i < NPAIRS)
        atomicAdd(&cnt[(omap[k * NPAIRS + i] >> 4) * KVOL + k], 1);
}

// 2-level exclusive scan over NKEYS counters (165 blocks x 2048 items).
__global__ __launch_bounds__(256) void scan1_kernel(const int* __restrict__ cnt,
                                                    int* __restrict__ offs,
                                                    int* __restrict__ bsum) {
    __shared__ int s[256];
    const int t = threadIdx.x;
    const int base = blockIdx.x * SCAN_ITEMS + t * 8;
    int v[8]; int sum = 0;
    #pragma unroll
    for (int i = 0; i < 8; ++i) {
        const int idx = base + i;
        v[i] = (idx < NKEYS) ? cnt[idx] : 0;
        sum += v[i];
    }
    s[t] = sum;
    __syncthreads();
    for (int off = 1; off < 256; off <<= 1) {         // Hillis-Steele inclusive
        const int x = (t >= off) ? s[t - off] : 0;
        __syncthreads();
        s[t] += x;
        __syncthreads();
    }
    if (t == 255) bsum[blockIdx.x] = s[255];
    int run = s[t] - sum;                             // exclusive prefix of this thread
    #pragma unroll
    for (int i = 0; i < 8; ++i) {
        const int idx = base + i;
        if (idx < NKEYS) offs[idx] = run;
        run += v[i];
    }
}

__global__ __launch_bounds__(256) void scan2_kernel(int* __restrict__ bsum) {
    __shared__ int s[256];
    const int t = threadIdx.x;
    const int v = (t < NSCANB) ? bsum[t] : 0;
    s[t] = v;
    __syncthreads();
    for (int off = 1; off < 256; off <<= 1) {
        const int x = (t >= off) ? s[t - off] : 0;
        __syncthreads();
        s[t] += x;
        __syncthreads();
    }
    if (t < NSCANB) bsum[t] = s[t] - v;               // exclusive block offsets
}

__global__ __launch_bounds__(256) void scan3_kernel(int* __restrict__ offs,
                                                    int* __restrict__ cursor,
                                                    const int* __restrict__ bsum) {
    const int base = blockIdx.x * SCAN_ITEMS + threadIdx.x * 8;
    const int add = bsum[blockIdx.x];
    if (blockIdx.x == 0 && threadIdx.x == 0) offs[NKEYS] = NPAIRS_TOT;  // sentinel
    #pragma unroll
    for (int i = 0; i < 8; ++i) {
        const int idx = base + i;
        if (idx < NKEYS) {
            const int v = offs[idx] + add;
            offs[idx] = v;
            cursor[idx] = v;                          // fill cursors start at bucket base
        }
    }
}

// payload = in_row (18b) | local_out_row (4b) << 18
__global__ __launch_bounds__(256) void fill_kernel(const int* __restrict__ imap,
                                                   const int* __restrict__ omap,
                                                   int* __restrict__ cursor,
                                                   unsigned* __restrict__ payload) {
    const int k = blockIdx.y;
    const int i = blockIdx.x * 256 + threadIdx.x;
    if (i < NPAIRS) {
        const int o = omap[k * NPAIRS + i];
        const int key = (o >> 4) * KVOL + k;
        const int pos = atomicAdd(&cursor[key], 1);
        payload[pos] = (unsigned)imap[k * NPAIRS + i] | ((unsigned)(o & 15) << 18);
    }
}

// ---------- output-stationary conv, latency-decoupled ----------
// R4 post-mortem: all pipes idle (HBM 2.6%, VALU 3.5%, MFMA 1.8%) -> latency-bound.
// The per-k serial chain (offs load -> payload -> fb gather -> mfma -> ds -> block
// barrier) had ~1 memory op in flight per wave. Restructure:
//   * block = 1 TILE; 4 waves take the tile's ~27 chunks round-robin (4x less
//     serial depth per wave, no mid-kernel barrier; LDS atomics absorb collisions)
//   * chunk address stream derives from 28 offs ints held in registers (one
//     lane-load + shfl) -> payloads prefetched one chunk-PAIR ahead, weight+feats
//     loads issued for both chunks of a pair before either is computed
//   * branch-free load path (clamped indices); only ds_add keeps the < cnt guard
__global__ __launch_bounds__(256, 3) void conv_gather_kernel(
    const ushort* __restrict__ fb,        // bf16 feats [NPTS][64]
    const ushort* __restrict__ wt,        // bf16 [KVOL][COUT][CIN]
    const unsigned* __restrict__ payload,
    const int* __restrict__ offs,         // NKEYS+1 (sentinel)
    const float* __restrict__ gamma,
    const float* __restrict__ beta,
    const float* __restrict__ rmean,
    const float* __restrict__ rvar,
    float* __restrict__ out)
{
    __shared__ float tile[16 * 65];       // one 16-row tile, shared by 4 waves
    const int lane = threadIdx.x & 63;
    const int wave = threadIdx.x >> 6;
    const int m = lane & 15;
    const int q = lane >> 4;
    const int t = blockIdx.x;

    for (int i = threadIdx.x; i < 16 * 65; i += 256) tile[i] = 0.f;
    __syncthreads();

    // bucket bounds E[0..27] live in one register per lane
    const int li = lane < 27 ? lane : 27;
    const int e_lane = offs[t * KVOL + li];
    auto E = [&](int kk) { return __shfl(e_lane, kk); };

    // ---- chunk walk (wave-uniform); yields every 4th chunk to this wave ----
    int wk_ = 0, wbase = E(0), we1 = E(1);
    while (wk_ < KVOL && wbase >= we1) { ++wk_; if (wk_ < KVOL) { wbase = E(wk_); we1 = E(wk_ + 1); } }
    int skip = wave;
    auto adv1 = [&]() {
        wbase += 16;
        if (wbase >= we1) {
            do { ++wk_; } while (wk_ < KVOL && E(wk_) == E(wk_ + 1));
            if (wk_ < KVOL) { wbase = E(wk_); we1 = E(wk_ + 1); }
        }
    };
    auto next_own = [&](int& mk, int& mb, int& me) -> bool {
        while (skip > 0 && wk_ < KVOL) { adv1(); --skip; }
        if (wk_ >= KVOL) { mk = 0; mb = 0; me = 0; return false; }   // dead: cnt=0
        mk = wk_; mb = wbase; me = we1;
        skip = 4;
        return true;
    };
    auto pidx = [&](int b) { int i = b + m; return i < NPAIRS_TOT ? i : NPAIRS_TOT - 1; };

    struct ChunkRegs { short8 W[2][4]; short8 a0, a1; };
    auto issue = [&](int kk, unsigned pl, ChunkRegs& cr) {
        const ushort* wb = wt + (kk << 12);
        #pragma unroll
        for (int h = 0; h < 2; ++h)
            #pragma unroll
            for (int nt = 0; nt < 4; ++nt)
                cr.W[h][nt] = *(const short8*)(wb + (nt * 16 + m) * 64 + h * 32 + q * 8);
        const ushort* fr = fb + (size_t)(pl & 0x3FFFFu) * 64 + q * 8;
        cr.a0 = *(const short8*)(fr);
        cr.a1 = *(const short8*)(fr + 32);
    };
    auto compute = [&](const ChunkRegs& cr, int bb, int ee, unsigned pl) {
        unsigned plr[4];
        #pragma unroll
        for (int r = 0; r < 4; ++r) plr[r] = (unsigned)__shfl((int)pl, q * 4 + r);
        f32x4 acc[4];
        #pragma unroll
        for (int nt = 0; nt < 4; ++nt) acc[nt] = (f32x4){0.f, 0.f, 0.f, 0.f};
        #pragma unroll
        for (int nt = 0; nt < 4; ++nt) {
            acc[nt] = __builtin_amdgcn_mfma_f32_16x16x32_bf16(cr.a0, cr.W[0][nt], acc[nt], 0, 0, 0);
            acc[nt] = __builtin_amdgcn_mfma_f32_16x16x32_bf16(cr.a1, cr.W[1][nt], acc[nt], 0, 0, 0);
        }
        const int cnt = ee - bb;                      // 0 for dead chunks
        #pragma unroll
        for (int r = 0; r < 4; ++r) {
            if (q * 4 + r < cnt) {
                const int l = (int)((plr[r] >> 18) & 15u);
                #pragma unroll
                for (int nt = 0; nt < 4; ++nt)
                    atomicAdd(&tile[l * 65 + nt * 16 + m], acc[nt][r]);
            }
        }
    };

    // ---- pipelined pair loop ----
    int kA, bA, eA, kB, bB, eB;
    bool lvA = next_own(kA, bA, eA);
    next_own(kB, bB, eB);
    unsigned plA = payload[pidx(bA)];
    unsigned plB = payload[pidx(bB)];

    while (lvA) {
        int kC, bC, eC, kD, bD, eD;
        const bool lvC = next_own(kC, bC, eC);
        next_own(kD, bD, eD);
        const unsigned plC = payload[pidx(bC)];       // next pair: issued now, used next iter
        const unsigned plD = payload[pidx(bD)];

        ChunkRegs crA, crB;
        issue(kA, plA, crA);                          // W + feats for both chunks in flight
        issue(kB, plB, crB);
        compute(crA, bA, eA, plA);
        compute(crB, bB, eB, plB);

        lvA = lvC;
        kA = kC; bA = bC; eA = eC; plA = plC;
        kB = kD; bB = bD; eB = eD; plB = plD;
    }

    __syncthreads();                                  // cross-wave ds_adds done
    const int i0 = threadIdx.x * 4;                   // 16x64 outputs, 4/thread
    const int row = i0 >> 6, col = i0 & 63;
    f32x4 o;
    #pragma unroll
    for (int e = 0; e < 4; ++e) {
        const int c = col + e;
        const float sc = gamma[c] * rsqrtf(rvar[c] + BN_EPS);
        const float bi = beta[c] - rmean[c] * sc;
        o[e] = fmaxf(tile[row * 65 + c] * sc + bi, 0.f);
    }
    *(f32x4*)(out + ((size_t)t * 16 + row) * COUT + col) = o;
}

extern "C" void kernel_launch(void* const* d_in, const int* in_sizes, int n_in,
                              void* d_out, int out_size, void* d_ws, size_t ws_size,
                              hipStream_t stream) {
    const float* feats = (const float*)d_in[0];
    const float* wk    = (const float*)d_in[1];
    const float* gamma = (const float*)d_in[2];
    const float* beta  = (const float*)d_in[3];
    const float* rmean = (const float*)d_in[4];
    const float* rvar  = (const float*)d_in[5];
    const int* imap    = (const int*)d_in[6];
    const int* omap    = (const int*)d_in[7];
    float* out         = (float*)d_out;

    // workspace carve — byte-verified disjoint:
    //   cnt     [0        , 1,350,000)
    //   offs    [2,097,152, 3,447,156)   (NKEYS+1 ints)
    //   bsum    [4,194,304, 4,194,964)
    //   cursor  [5,242,880, 6,592,880)
    //   wt      [7,340,032, 7,561,216)
    //   payload [8,388,608, 19,188,608)
    //   fb      [20,971,520, 46,571,520)
    char* ws = (char*)d_ws;
    int* cnt          = (int*)(ws);
    int* offs         = (int*)(ws + (2u << 20));
    int* bsum         = (int*)(ws + (4u << 20));
    int* cursor       = (int*)(ws + (5u << 20));
    ushort* wt        = (ushort*)(ws + (7u << 20));
    unsigned* payload = (unsigned*)(ws + (8u << 20));
    ushort* fb        = (ushort*)(ws + (20u << 20));

    hipMemsetAsync(cnt, 0, NKEYS * sizeof(int), stream);
    fprep_kernel<<<NPTS * CIN / (256 * 8), 256, 0, stream>>>(feats, fb);
    wprep_kernel<<<(KVOL * CIN * COUT + 255) / 256, 256, 0, stream>>>(wk, wt);
    hist_kernel<<<dim3((NPAIRS + 255) / 256, KVOL), 256, 0, stream>>>(omap, cnt);
    scan1_kernel<<<NSCANB, 256, 0, stream>>>(cnt, offs, bsum);
    scan2_kernel<<<1, 256, 0, stream>>>(bsum);
    scan3_kernel<<<NSCANB, 256, 0, stream>>>(offs, cursor, bsum);
    fill_kernel<<<dim3((NPAIRS + 255) / 256, KVOL), 256, 0, stream>>>(imap, omap, cursor, payload);
    conv_gather_kernel<<<NTILES, 256, 0, stream>>>(
        fb, wt, payload, offs, gamma, beta, rmean, rvar, out);
}

// Round 6
// 1362.715 us; speedup vs baseline: 1.0558x; 1.0430x over previous
//
#include <hip/hip_runtime.h>
#include <hip/hip_bf16.h>

#define NPTS 200000
#define CIN 64
#define COUT 64
#define KVOL 27
#define NPAIRS 100000
#define NPAIRS_TOT (KVOL * NPAIRS)                       // 2,700,000
#define TROWS 64                                         // output rows per tile
#define NTILES (NPTS / TROWS)                            // 3125
#define NKEYS (NTILES * KVOL)                            // 84,375 (tile,k) buckets
#define SCAN_ITEMS 2048
#define NSCANB ((NKEYS + SCAN_ITEMS - 1) / SCAN_ITEMS)   // 42
#define BN_EPS 1e-5f

static_assert(NPTS % TROWS == 0, "tiles");
static_assert(NSCANB <= 256, "single-block top scan");
static_assert(NPTS * CIN % (256 * 8) == 0, "fprep exact grid");
static_assert(NPAIRS_TOT < (1 << 22), "meta base pack");

typedef __attribute__((ext_vector_type(8))) short short8;   // 8 bf16 (4 VGPRs)
typedef __attribute__((ext_vector_type(4))) float f32x4;

__device__ inline ushort f2bf(float x) {
    union { __hip_bfloat16 h; ushort u; } cv;
    cv.h = __float2bfloat16(x);   // RNE
    return cv.u;
}

// ---------- preprocessing (counting sort by (out_tile64, k)) ----------

// feats fp32 [NPTS][64] -> bf16 [NPTS][64] (row = 128B)
__global__ __launch_bounds__(256) void fprep_kernel(const float* __restrict__ feats,
                                                    ushort* __restrict__ fbuf) {
    const int i = blockIdx.x * 256 + threadIdx.x;     // 8 elems/thread, exact grid
    const f32x4 v0 = *(const f32x4*)(feats + (size_t)i * 8);
    const f32x4 v1 = *(const f32x4*)(feats + (size_t)i * 8 + 4);
    short8 o;
    #pragma unroll
    for (int e = 0; e < 4; ++e) {
        o[e]     = (short)f2bf(v0[e]);
        o[e + 4] = (short)f2bf(v1[e]);
    }
    *(short8*)(fbuf + (size_t)i * 8) = o;
}

// W[k][cin][cout] fp32  ->  Wt[k][cout][cin] bf16 (B-frags load as 16B)
__global__ __launch_bounds__(256) void wprep_kernel(const float* __restrict__ wk,
                                                    ushort* __restrict__ wt) {
    const int i = blockIdx.x * 256 + threadIdx.x;     // over KVOL*64*64 = 110,592
    if (i >= KVOL * CIN * COUT) return;
    const int k = i >> 12, r = i & 4095, co = r >> 6, ci = r & 63;
    wt[i] = f2bf(wk[(k << 12) | (ci << 6) | co]);
}

// 2D grid: blockIdx.y = k
__global__ __launch_bounds__(256) void hist_kernel(const int* __restrict__ omap,
                                                   int* __restrict__ cnt) {
    const int k = blockIdx.y;
    const int i = blockIdx.x * 256 + threadIdx.x;
    if (i < NPAIRS)
        atomicAdd(&cnt[(omap[k * NPAIRS + i] >> 6) * KVOL + k], 1);
}

// 2-level exclusive scan over NKEYS counters.
__global__ __launch_bounds__(256) void scan1_kernel(const int* __restrict__ cnt,
                                                    int* __restrict__ offs,
                                                    int* __restrict__ bsum) {
    __shared__ int s[256];
    const int t = threadIdx.x;
    const int base = blockIdx.x * SCAN_ITEMS + t * 8;
    int v[8]; int sum = 0;
    #pragma unroll
    for (int i = 0; i < 8; ++i) {
        const int idx = base + i;
        v[i] = (idx < NKEYS) ? cnt[idx] : 0;
        sum += v[i];
    }
    s[t] = sum;
    __syncthreads();
    for (int off = 1; off < 256; off <<= 1) {         // Hillis-Steele inclusive
        const int x = (t >= off) ? s[t - off] : 0;
        __syncthreads();
        s[t] += x;
        __syncthreads();
    }
    if (t == 255) bsum[blockIdx.x] = s[255];
    int run = s[t] - sum;
    #pragma unroll
    for (int i = 0; i < 8; ++i) {
        const int idx = base + i;
        if (idx < NKEYS) offs[idx] = run;
        run += v[i];
    }
}

__global__ __launch_bounds__(256) void scan2_kernel(int* __restrict__ bsum) {
    __shared__ int s[256];
    const int t = threadIdx.x;
    const int v = (t < NSCANB) ? bsum[t] : 0;
    s[t] = v;
    __syncthreads();
    for (int off = 1; off < 256; off <<= 1) {
        const int x = (t >= off) ? s[t - off] : 0;
        __syncthreads();
        s[t] += x;
        __syncthreads();
    }
    if (t < NSCANB) bsum[t] = s[t] - v;
}

__global__ __launch_bounds__(256) void scan3_kernel(int* __restrict__ offs,
                                                    int* __restrict__ cursor,
                                                    const int* __restrict__ bsum) {
    const int base = blockIdx.x * SCAN_ITEMS + threadIdx.x * 8;
    const int add = bsum[blockIdx.x];
    if (blockIdx.x == 0 && threadIdx.x == 0) offs[NKEYS] = NPAIRS_TOT;  // sentinel
    #pragma unroll
    for (int i = 0; i < 8; ++i) {
        const int idx = base + i;
        if (idx < NKEYS) {
            const int v = offs[idx] + add;
            offs[idx] = v;
            cursor[idx] = v;
        }
    }
}

// payload = in_row (18b) | local_out_row (6b) << 18
__global__ __launch_bounds__(256) void fill_kernel(const int* __restrict__ imap,
                                                   const int* __restrict__ omap,
                                                   int* __restrict__ cursor,
                                                   unsigned* __restrict__ payload) {
    const int k = blockIdx.y;
    const int i = blockIdx.x * 256 + threadIdx.x;
    if (i < NPAIRS) {
        const int o = omap[k * NPAIRS + i];
        const int key = (o >> 6) * KVOL + k;
        const int pos = atomicAdd(&cursor[key], 1);
        payload[pos] = (unsigned)imap[k * NPAIRS + i] | ((unsigned)(o & 63) << 18);
    }
}

// ---------- output-stationary conv, deep-pipelined gather ----------
// R5 post-mortem: invariant ~5G random rows/s == (2 gathers in flight/wave x 14
// waves) / ~700cy latency -> MLP-bound. Fixes: (a) 6-phase static pipeline:
// payload 6 chunks ahead, feats 3 chunks ahead (48 rows in flight/wave);
// (b) tile=64 rows: buckets mean 32 entries -> ~90% chunk-slot utilization,
// 207K chunks (vs 340K), W amortized over the bucket (reload only on k change).
__global__ __launch_bounds__(256, 4) void conv_gather_kernel(
    const ushort* __restrict__ fbuf,      // bf16 feats [NPTS][64]
    const ushort* __restrict__ wt,        // bf16 [KVOL][COUT][CIN]
    const unsigned* __restrict__ payload,
    const int* __restrict__ offs,         // NKEYS+1 (sentinel)
    const float* __restrict__ gamma,
    const float* __restrict__ beta,
    const float* __restrict__ rmean,
    const float* __restrict__ rvar,
    float* __restrict__ out)
{
    __shared__ float tile[TROWS * 65];    // 16.64 KB, shared by 4 waves
    const int lane = threadIdx.x & 63;
    const int wave = threadIdx.x >> 6;
    const int m = lane & 15;
    const int q = lane >> 4;
    const int t = blockIdx.x;

    for (int i = threadIdx.x; i < TROWS * 65; i += 256) tile[i] = 0.f;
    __syncthreads();

    // bucket bounds E[0..27] in one register per lane
    const int li = lane < KVOL ? lane : KVOL;
    const int e_lane = offs[t * KVOL + li];
    auto E = [&](int kk) { return __shfl(e_lane, kk); };

    // wave owns k = wave, wave+4, ... (bucket-consecutive -> W amortized)
    int kk = wave, cb = 0, ce = 0;
    while (kk < KVOL) { cb = E(kk); ce = E(kk + 1); if (cb < ce) break; kk += 4; }
    int total = 0;
    for (int k2 = wave; k2 < KVOL; k2 += 4) total += (E(k2 + 1) - E(k2) + 15) >> 4;

    // packed meta: base(22b) | k(5b)<<22 | cnt(5b)<<27  (dead = 0)
    auto nextc = [&]() -> unsigned {
        if (kk >= KVOL) return 0u;
        int cnt = ce - cb; if (cnt > 16) cnt = 16;
        const unsigned me = (unsigned)cb | ((unsigned)kk << 22) | ((unsigned)cnt << 27);
        cb += 16;
        if (cb >= ce) {
            kk += 4;
            while (kk < KVOL) { cb = E(kk); ce = E(kk + 1); if (cb < ce) break; kk += 4; }
        }
        return me;
    };
    auto ploadi = [&](unsigned me) -> unsigned {
        unsigned idx = (me & 0x3FFFFFu) + (unsigned)m;
        if (idx > NPAIRS_TOT - 1) idx = NPAIRS_TOT - 1;   // tail clamp (stays in payload)
        return payload[idx];
    };

    unsigned meq[6], plq[6];
    short8 ga0[3], ga1[3];
    short8 W0[4], W1[4];
    int kcur = -1;

    #pragma unroll
    for (int j = 0; j < 6; ++j) { meq[j] = nextc(); plq[j] = ploadi(meq[j]); }
    #pragma unroll
    for (int j = 0; j < 3; ++j) {
        const ushort* fr = fbuf + (size_t)(plq[j] & 0x3FFFFu) * 64 + q * 8;
        ga0[j] = *(const short8*)(fr);
        ga1[j] = *(const short8*)(fr + 32);
    }

    int i = 0;
    while (i < total) {
        #pragma unroll
        for (int ph = 0; ph < 6; ++ph) {
            if (i < total) {
                const unsigned me = meq[ph];
                const unsigned pl = plq[ph];
                const int mk = (int)((me >> 22) & 31u);
                const int mc = (int)(me >> 27);
                if (mc && mk != kcur) {               // W reload only on k change
                    const ushort* wb = wt + (mk << 12);
                    #pragma unroll
                    for (int nt = 0; nt < 4; ++nt) {
                        W0[nt] = *(const short8*)(wb + (nt * 16 + m) * 64 + q * 8);
                        W1[nt] = *(const short8*)(wb + (nt * 16 + m) * 64 + 32 + q * 8);
                    }
                    kcur = mk;
                }
                unsigned plr[4];
                #pragma unroll
                for (int r = 0; r < 4; ++r) plr[r] = (unsigned)__shfl((int)pl, q * 4 + r);

                f32x4 acc[4];
                #pragma unroll
                for (int nt = 0; nt < 4; ++nt) acc[nt] = (f32x4){0.f, 0.f, 0.f, 0.f};
                #pragma unroll
                for (int nt = 0; nt < 4; ++nt) {
                    acc[nt] = __builtin_amdgcn_mfma_f32_16x16x32_bf16(ga0[ph % 3], W0[nt], acc[nt], 0, 0, 0);
                    acc[nt] = __builtin_amdgcn_mfma_f32_16x16x32_bf16(ga1[ph % 3], W1[nt], acc[nt], 0, 0, 0);
                }
                #pragma unroll
                for (int r = 0; r < 4; ++r) {
                    if (q * 4 + r < mc) {
                        const int l = (int)((plr[r] >> 18) & 63u);
                        #pragma unroll
                        for (int nt = 0; nt < 4; ++nt)
                            atomicAdd(&tile[l * 65 + nt * 16 + m], acc[nt][r]);
                    }
                }
                // regather slot ph%3 for chunk i+3 (payload arrived ~3 iters ago)
                const ushort* fr = fbuf + (size_t)(plq[(ph + 3) % 6] & 0x3FFFFu) * 64 + q * 8;
                ga0[ph % 3] = *(const short8*)(fr);
                ga1[ph % 3] = *(const short8*)(fr + 32);
                // fetch meta + payload for chunk i+6 into slot ph
                meq[ph] = nextc();
                plq[ph] = ploadi(meq[ph]);
                ++i;
            }
        }
    }

    __syncthreads();                                  // all waves' ds_adds done
    const int col = (threadIdx.x * 4) & 63;           // 4 fixed cols per thread
    float sc4[4], bi4[4];
    #pragma unroll
    for (int e = 0; e < 4; ++e) {
        const float sc = gamma[col + e] * rsqrtf(rvar[col + e] + BN_EPS);
        sc4[e] = sc;
        bi4[e] = beta[col + e] - rmean[col + e] * sc;
    }
    #pragma unroll
    for (int p = 0; p < 4; ++p) {
        const int row = p * 16 + (threadIdx.x >> 4);
        f32x4 o;
        #pragma unroll
        for (int e = 0; e < 4; ++e)
            o[e] = fmaxf(tile[row * 65 + col + e] * sc4[e] + bi4[e], 0.f);
        *(f32x4*)(out + ((size_t)t * TROWS + row) * COUT + col) = o;
    }
}

extern "C" void kernel_launch(void* const* d_in, const int* in_sizes, int n_in,
                              void* d_out, int out_size, void* d_ws, size_t ws_size,
                              hipStream_t stream) {
    const float* feats = (const float*)d_in[0];
    const float* wk    = (const float*)d_in[1];
    const float* gamma = (const float*)d_in[2];
    const float* beta  = (const float*)d_in[3];
    const float* rmean = (const float*)d_in[4];
    const float* rvar  = (const float*)d_in[5];
    const int* imap    = (const int*)d_in[6];
    const int* omap    = (const int*)d_in[7];
    float* out         = (float*)d_out;

    // workspace carve — byte-verified disjoint:
    //   cnt     [0         ,    337,500)
    //   offs    [1,048,576 ,  1,386,080)   (NKEYS+1 ints)
    //   bsum    [1,572,864 ,  1,573,032)
    //   cursor  [2,097,152 ,  2,434,652)
    //   wt      [3,145,728 ,  3,366,912)
    //   payload [4,194,304 , 14,994,304)
    //   fb      [16,777,216, 42,377,216)   (<= 51.2MB ws, per R0)
    char* ws = (char*)d_ws;
    int* cnt          = (int*)(ws);
    int* offs         = (int*)(ws + (1u << 20));
    int* bsum         = (int*)(ws + 1572864u);
    int* cursor       = (int*)(ws + (2u << 20));
    ushort* wt        = (ushort*)(ws + (3u << 20));
    unsigned* payload = (unsigned*)(ws + (4u << 20));
    ushort* fbuf      = (ushort*)(ws + (16u << 20));

    hipMemsetAsync(cnt, 0, NKEYS * sizeof(int), stream);
    fprep_kernel<<<NPTS * CIN / (256 * 8), 256, 0, stream>>>(feats, fbuf);
    wprep_kernel<<<(KVOL * CIN * COUT + 255) / 256, 256, 0, stream>>>(wk, wt);
    hist_kernel<<<dim3((NPAIRS + 255) / 256, KVOL), 256, 0, stream>>>(omap, cnt);
    scan1_kernel<<<NSCANB, 256, 0, stream>>>(cnt, offs, bsum);
    scan2_kernel<<<1, 256, 0, stream>>>(bsum);
    scan3_kernel<<<NSCANB, 256, 0, stream>>>(offs, cursor, bsum);
    fill_kernel<<<dim3((NPAIRS + 255) / 256, KVOL), 256, 0, stream>>>(imap, omap, cursor, payload);
    conv_gather_kernel<<<NTILES, 256, 0, stream>>>(
        fbuf, wt, payload, offs, gamma, beta, rmean, rvar, out);
}